// Round 3
// baseline (2643.977 us; speedup 1.0000x reference)
//
#include <hip/hip_runtime.h>
#include <hip/hip_bf16.h>

// Problem constants (B, N, C fixed by reference)
#define BB 8
#define NN 2048
#define CC 256
#define GG 64        // C / NGRP groups of 4 channels
#define QQ 8

typedef unsigned short u16;

static __device__ __forceinline__ float b2f(u16 u) {
  union { unsigned int i; float f; } cv; cv.i = ((unsigned int)u) << 16; return cv.f;
}
static __device__ __forceinline__ u16 f2b(float f) {
  union { __hip_bfloat16 h; u16 u; } cv; cv.h = __float2bfloat16(f); return cv.u;
}
// dtype-flexible scalar load: flag ? float32 : bf16
static __device__ __forceinline__ float ldin(const void* p, size_t i, bool f32) {
  return f32 ? ((const float*)p)[i] : b2f(((const u16*)p)[i]);
}

// ---------------------------------------------------------------------------
// dtype detection (bf16 vs f32 inputs), as in round 2 — robust either way.
// ---------------------------------------------------------------------------
__global__ __launch_bounds__(256) void detect_kernel(const u16* __restrict__ sc,
                                                     int* __restrict__ flag)
{
  __shared__ int sh;
  if (threadIdx.x == 0) sh = 0;
  __syncthreads();
  int cnt = 0;
  for (int i = threadIdx.x; i < 2048; i += 256) {
    u16 w = sc[2 * i];
    int e = (w >> 7) & 0xFF;
    if (e >= 100 && e <= 130) cnt++;
  }
  atomicAdd(&sh, cnt);
  __syncthreads();
  if (threadIdx.x == 0) *flag = (sh < 1024) ? 1 : 0;   // 1 => float32 inputs
}

// ---------------------------------------------------------------------------
// K_f32[bl,i,j] = 0.5*(sc[b,i,j]+sc[b,j,i]) * sigmoid(dot(U[i],U[j]))
// bl = b - grp*4 (4 batches per phase; K reused across all Q steps)
// ---------------------------------------------------------------------------
__global__ __launch_bounds__(256) void build_k_kernel(
    const void* __restrict__ sc, const void* __restrict__ U,
    float* __restrict__ Kf, const int* __restrict__ flagp, int grp)
{
  const bool f32 = (*flagp != 0);
  const int bl = blockIdx.z;            // 0..3
  const int b  = grp * 4 + bl;
  const int i0 = blockIdx.y * 32;
  const int j0 = blockIdx.x * 32;
  const int tx = threadIdx.x;   // 0..31
  const int ty = threadIdx.y;   // 0..7
  const int t  = ty * 32 + tx;

  __shared__ float Ui[32][17];
  __shared__ float Uj[32][17];
  __shared__ float st[32][33];

  for (int s = t; s < 512; s += 256) {
    int rr = s >> 4, kk = s & 15;
    Ui[rr][kk] = ldin(U, (size_t)(i0 + rr) * 16 + kk, f32);
    Uj[rr][kk] = ldin(U, (size_t)(j0 + rr) * 16 + kk, f32);
  }
  const size_t scb = (size_t)b * NN * NN;
  for (int jj = ty; jj < 32; jj += 8)
    st[jj][tx] = ldin(sc, scb + (size_t)(j0 + jj) * NN + i0 + tx, f32);
  __syncthreads();

  const size_t kfb = (size_t)bl * NN * NN;
  for (int ii = ty; ii < 32; ii += 8) {
    float dot = 0.f;
    #pragma unroll
    for (int k = 0; k < 16; k++) dot += Ui[ii][k] * Uj[tx][k];
    float A = 1.0f / (1.0f + expf(-dot));
    float d = ldin(sc, scb + (size_t)(i0 + ii) * NN + j0 + tx, f32);
    Kf[kfb + (size_t)(i0 + ii) * NN + j0 + tx] = 0.5f * (d + st[tx][ii]) * A;
  }
}

// ---------------------------------------------------------------------------
// GroupNorm stats over y[b, 4g:4g+4, :]  (8192 elems per (b,g))
// ---------------------------------------------------------------------------
__global__ __launch_bounds__(256) void gn_stats_kernel(
    const void* __restrict__ y, float* __restrict__ murs,
    const int* __restrict__ flagp)
{
  const bool f32 = (*flagp != 0);
  const int bg = blockIdx.x;                    // b*64 + g
  float s = 0.f, ss = 0.f;
  if (f32) {
    const float* base = (const float*)y + (size_t)bg * 4 * NN;
    for (int i = threadIdx.x; i < 2048; i += 256) {
      float4 v = *(const float4*)(base + (size_t)i * 4);
      s  += v.x + v.y + v.z + v.w;
      ss += v.x*v.x + v.y*v.y + v.z*v.z + v.w*v.w;
    }
  } else {
    const u16* base = (const u16*)y + (size_t)bg * 4 * NN;
    for (int i = threadIdx.x; i < 2048; i += 256) {
      ushort4 v = *(const ushort4*)(base + (size_t)i * 4);
      float f0 = b2f(v.x), f1 = b2f(v.y), f2 = b2f(v.z), f3 = b2f(v.w);
      s  += f0 + f1 + f2 + f3;
      ss += f0*f0 + f1*f1 + f2*f2 + f3*f3;
    }
  }
  #pragma unroll
  for (int off = 32; off > 0; off >>= 1) {
    s  += __shfl_down(s, off, 64);
    ss += __shfl_down(ss, off, 64);
  }
  __shared__ float sh[8];
  const int w = threadIdx.x >> 6, ln = threadIdx.x & 63;
  if (ln == 0) { sh[w * 2] = s; sh[w * 2 + 1] = ss; }
  __syncthreads();
  if (threadIdx.x == 0) {
    float S  = sh[0] + sh[2] + sh[4] + sh[6];
    float SS = sh[1] + sh[3] + sh[5] + sh[7];
    float mu  = S / 8192.0f;
    float var = SS / 8192.0f - mu * mu;
    murs[bg * 2]     = mu;
    murs[bg * 2 + 1] = 1.0f / sqrtf(fmaxf(var, 0.f) + 1e-5f);
  }
}

// ---------------------------------------------------------------------------
// y_t[b,n,c] = sphere( GN(y)[b,c,n] * w + bias ), groups of 4 channels (f32)
// ---------------------------------------------------------------------------
__global__ __launch_bounds__(256) void y_tf_kernel(
    const void* __restrict__ y, const float* __restrict__ murs,
    const void* __restrict__ gw, const void* __restrict__ gb,
    float* __restrict__ yt, const int* __restrict__ flagp)
{
  const bool f32 = (*flagp != 0);
  const int b = blockIdx.y;
  const int n = blockIdx.x * 64 + threadIdx.x;
  for (int g = threadIdx.y; g < GG; g += 4) {
    float mu = murs[(b * GG + g) * 2];
    float rs = murs[(b * GG + g) * 2 + 1];
    float v[4];
    #pragma unroll
    for (int k = 0; k < 4; k++) {
      int c = 4 * g + k;
      float val = (ldin(y, ((size_t)b * CC + c) * NN + n, f32) - mu) * rs;
      v[k] = val * ldin(gw, c, f32) + ldin(gb, c, f32);
    }
    float n2 = v[0]*v[0] + v[1]*v[1] + v[2]*v[2] + v[3]*v[3];
    float scl = 1.0f / sqrtf(fmaxf(n2, 1e-6f));
    float4 o; o.x = v[0]*scl; o.y = v[1]*scl; o.z = v[2]*scl; o.w = v[3]*scl;
    *(float4*)(yt + ((size_t)b * NN + n) * CC + 4 * g) = o;
  }
}

// ---------------------------------------------------------------------------
// x init: sphere-normalize x -> f32 state (the GEMM B operand reads xst)
// ---------------------------------------------------------------------------
__global__ __launch_bounds__(256) void x_init_kernel(
    const void* __restrict__ x, float* __restrict__ xst,
    const int* __restrict__ flagp)
{
  const bool f32 = (*flagp != 0);
  const int b = blockIdx.y;
  const int n = blockIdx.x * 64 + threadIdx.x;
  for (int g = threadIdx.y; g < GG; g += 4) {
    size_t idx = ((size_t)b * NN + n) * CC + 4 * g;
    float v[4];
    if (f32) {
      float4 u4 = *(const float4*)((const float*)x + idx);
      v[0] = u4.x; v[1] = u4.y; v[2] = u4.z; v[3] = u4.w;
    } else {
      ushort4 u = *(const ushort4*)((const u16*)x + idx);
      v[0] = b2f(u.x); v[1] = b2f(u.y); v[2] = b2f(u.z); v[3] = b2f(u.w);
    }
    float n2 = v[0]*v[0] + v[1]*v[1] + v[2]*v[2] + v[3]*v[3];
    float scl = 1.0f / sqrtf(fmaxf(n2, 1e-6f));
    float4 o; o.x = v[0]*scl; o.y = v[1]*scl; o.z = v[2]*scl; o.w = v[3]*scl;
    *(float4*)(xst + idx) = o;
  }
}

// ---------------------------------------------------------------------------
// f32 GEMM (VALU): coup[b,n,c] = sum_m K[bl,n,m] * xst[b,m,c]
// BM=64, BN=64, BK=16; 256 threads, 4x4 acc/thread; register prefetch.
// Grid: (CC/64, NN/64, 4 local batches) = (4, 32, 4) = 512 blocks (2/CU).
// ---------------------------------------------------------------------------
__global__ __launch_bounds__(256, 2) void gemm_f32_kernel(
    const float* __restrict__ Kf, const float* __restrict__ xst,
    float* __restrict__ coup, int grp)
{
  const int bl = blockIdx.z;
  const int b  = grp * 4 + bl;
  const int m0 = blockIdx.y * 64;
  const int c0 = blockIdx.x * 64;
  const float* A  = Kf  + (size_t)bl * NN * NN;
  const float* Bx = xst + (size_t)b * NN * CC;

  __shared__ float As[16][68];   // [k][m], +4 pad
  __shared__ float Bs[16][64];   // [k][c]

  const int t  = threadIdx.x;
  const int tx = t & 15;
  const int ty = t >> 4;

  const int ar = t >> 2;         // A row 0..63
  const int ak = (t & 3) * 4;    // A k offset {0,4,8,12}
  const int bk = t >> 4;         // B k 0..15
  const int bc = (t & 15) * 4;   // B col 0..60

  float acc[4][4];
  #pragma unroll
  for (int i = 0; i < 4; i++)
    #pragma unroll
    for (int j = 0; j < 4; j++) acc[i][j] = 0.f;

  float4 pa = *(const float4*)(A  + (size_t)(m0 + ar) * NN + ak);
  float4 pb = *(const float4*)(Bx + (size_t)bk * CC + c0 + bc);

  for (int k0 = 0; k0 < NN; k0 += 16) {
    __syncthreads();
    As[ak + 0][ar] = pa.x;
    As[ak + 1][ar] = pa.y;
    As[ak + 2][ar] = pa.z;
    As[ak + 3][ar] = pa.w;
    *(float4*)&Bs[bk][bc] = pb;
    __syncthreads();
    const int kn = k0 + 16;
    if (kn < NN) {
      pa = *(const float4*)(A  + (size_t)(m0 + ar) * NN + kn + ak);
      pb = *(const float4*)(Bx + (size_t)(kn + bk) * CC + c0 + bc);
    }
    #pragma unroll
    for (int k = 0; k < 16; k++) {
      float4 av = *(const float4*)&As[k][ty * 4];
      float4 bv = *(const float4*)&Bs[k][tx * 4];
      acc[0][0] += av.x * bv.x; acc[0][1] += av.x * bv.y;
      acc[0][2] += av.x * bv.z; acc[0][3] += av.x * bv.w;
      acc[1][0] += av.y * bv.x; acc[1][1] += av.y * bv.y;
      acc[1][2] += av.y * bv.z; acc[1][3] += av.y * bv.w;
      acc[2][0] += av.z * bv.x; acc[2][1] += av.z * bv.y;
      acc[2][2] += av.z * bv.z; acc[2][3] += av.z * bv.w;
      acc[3][0] += av.w * bv.x; acc[3][1] += av.w * bv.y;
      acc[3][2] += av.w * bv.z; acc[3][3] += av.w * bv.w;
    }
  }

  #pragma unroll
  for (int i = 0; i < 4; i++) {
    float4 o; o.x = acc[i][0]; o.y = acc[i][1]; o.z = acc[i][2]; o.w = acc[i][3];
    *(float4*)(coup + ((size_t)b * NN + m0 + ty * 4 + i) * CC + c0 + tx * 4) = o;
  }
}

// ---------------------------------------------------------------------------
// One Kuramoto step (pointwise): force, tangent projection, omega, renorm
// ---------------------------------------------------------------------------
__global__ __launch_bounds__(256) void step_kernel(
    float* __restrict__ xst, const float* __restrict__ coup,
    const float* __restrict__ yt, const void* __restrict__ omega,
    const void* __restrict__ gamma, void* __restrict__ outbase, size_t qoff,
    const int* __restrict__ flagp, int grp)
{
  const bool f32 = (*flagp != 0);
  const int b = grp * 4 + blockIdx.y;
  const int n = blockIdx.x * 64 + threadIdx.x;
  const float gm = ldin(gamma, 0, f32);
  for (int g = threadIdx.y; g < GG; g += 4) {
    size_t idx = ((size_t)b * NN + n) * CC + 4 * g;
    float4 xc4 = *(const float4*)(xst + idx);
    float4 cp4 = *(const float4*)(coup + idx);
    float4 yv4 = *(const float4*)(yt + idx);
    float xc[4] = { xc4.x, xc4.y, xc4.z, xc4.w };
    float f[4]  = { cp4.x + yv4.x, cp4.y + yv4.y, cp4.z + yv4.z, cp4.w + yv4.w };
    float sim = xc[0]*f[0] + xc[1]*f[1] + xc[2]*f[2] + xc[3]*f[3];
    float om0 = fabsf(ldin(omega, 2 * g, f32));
    float om1 = fabsf(ldin(omega, 2 * g + 1, f32));
    float d0 =  om0 * xc[1] + (f[0] - sim * xc[0]);
    float d1 = -om0 * xc[0] + (f[1] - sim * xc[1]);
    float d2 =  om1 * xc[3] + (f[2] - sim * xc[2]);
    float d3 = -om1 * xc[2] + (f[3] - sim * xc[3]);
    float v[4] = { xc[0] + gm * d0, xc[1] + gm * d1, xc[2] + gm * d2, xc[3] + gm * d3 };
    float n2 = v[0]*v[0] + v[1]*v[1] + v[2]*v[2] + v[3]*v[3];
    float scl = 1.0f / sqrtf(fmaxf(n2, 1e-6f));
    float xn[4] = { v[0]*scl, v[1]*scl, v[2]*scl, v[3]*scl };
    float4 o; o.x = xn[0]; o.y = xn[1]; o.z = xn[2]; o.w = xn[3];
    *(float4*)(xst + idx) = o;
    if (f32) {
      *(float4*)((float*)outbase + qoff + idx) = o;
    } else {
      ushort4 ob;
      ob.x = f2b(xn[0]); ob.y = f2b(xn[1]); ob.z = f2b(xn[2]); ob.w = f2b(xn[3]);
      *(ushort4*)((u16*)outbase + qoff + idx) = ob;
    }
  }
}

// ---------------------------------------------------------------------------
extern "C" void kernel_launch(void* const* d_in, const int* in_sizes, int n_in,
                              void* d_out, int out_size, void* d_ws, size_t ws_size,
                              hipStream_t stream) {
  const void* x     = d_in[0];
  const void* y     = d_in[1];
  const void* sc    = d_in[2];
  const void* U     = d_in[3];
  const void* omega = d_in[4];
  const void* gw    = d_in[5];
  const void* gb    = d_in[6];
  const void* gamma = d_in[7];
  // d_in[8] = Q (int32) — fixed at 8 by the problem setup.
  char* ws = (char*)d_ws;

  // Workspace layout (total ~117.5 MB; stays under the 125.8 MB footprint
  // already exercised without fault in round 2)
  const size_t BNC = (size_t)BB * NN * CC;             // 4,194,304
  float* Kf   = (float*)(ws);                          // 4 batches f32: 67,108,864 B
  float* yt   = (float*)(ws + 67108864);               // 16,777,216 B
  float* xst  = (float*)(ws + 83886080);               // 16,777,216 B
  float* coup = (float*)(ws + 100663296);              // 16,777,216 B
  float* murs = (float*)(ws + 117440512);              // 4 KB
  int*   flag = (int*)  (ws + 117444608);              // 4 B

  detect_kernel<<<dim3(1), dim3(256), 0, stream>>>((const u16*)sc, flag);
  gn_stats_kernel<<<dim3(512), dim3(256), 0, stream>>>(y, murs, flag);
  y_tf_kernel<<<dim3(32, 8), dim3(64, 4), 0, stream>>>(y, murs, gw, gb, yt, flag);
  x_init_kernel<<<dim3(32, 8), dim3(64, 4), 0, stream>>>(x, xst, flag);

  for (int grp = 0; grp < 2; grp++) {
    build_k_kernel<<<dim3(64, 64, 4), dim3(32, 8), 0, stream>>>(sc, U, Kf, flag, grp);
    for (int q = 0; q < QQ; q++) {
      gemm_f32_kernel<<<dim3(4, 32, 4), dim3(256), 0, stream>>>(Kf, xst, coup, grp);
      step_kernel<<<dim3(32, 4), dim3(64, 4), 0, stream>>>(
          xst, coup, yt, omega, gamma, d_out, (size_t)q * BNC, flag, grp);
    }
  }
}